// Round 17
// baseline (75.194 us; speedup 1.0000x reference)
//
#include <hip/hip_runtime.h>
#include <hip/hip_bf16.h>
#include <math.h>

typedef _Float16 h16;
typedef h16   v4h __attribute__((ext_vector_type(4)));
typedef h16   v8h __attribute__((ext_vector_type(8)));
typedef h16   h2  __attribute__((ext_vector_type(2)));
typedef float v4f __attribute__((ext_vector_type(4)));

#define T_SEQ 2048
#define BATCH 16
#define NTOK  (BATCH * T_SEQ)
#define C_DIM 64
#define N_H   4
#define HD    16
#define FF    128
#define EPS_LN 1e-5f
#define MFMA16 __builtin_amdgcn_mfma_f32_16x16x16f16
#define MFMA32K __builtin_amdgcn_mfma_f32_16x16x32_f16
// q pre-scale: hd^-0.5 * log2(e) * 1024 (Schraudolph FMA fused into QK^T MFMA C-op)
#define QSCALE (0.25f * 1.44269504089f * 1024.0f)
#define BMAGIC (12582912.0f + 15316.0f)   // 1.5*2^23 + (15360-44)

static __device__ __forceinline__ float frcp(float x) {
#if __has_builtin(__builtin_amdgcn_rcpf)
    return __builtin_amdgcn_rcpf(x);
#else
    return 1.0f / x;
#endif
}
static __device__ __forceinline__ float frsq(float x) {
#if __has_builtin(__builtin_amdgcn_rsqf)
    return __builtin_amdgcn_rsqf(x);
#else
    return rsqrtf(x);
#endif
}
static __device__ __forceinline__ float fdot2p(h2 a, float acc) {
#if __has_builtin(__builtin_amdgcn_fdot2)
    const h2 one2 = {(h16)1.0f, (h16)1.0f};
    return __builtin_amdgcn_fdot2(a, one2, acc, false);
#else
    return acc + (float)a[0] + (float)a[1];
#endif
}
static __device__ __forceinline__ v4h cvt4(v4f f) {
    v4h r; r[0]=(h16)f[0]; r[1]=(h16)f[1]; r[2]=(h16)f[2]; r[3]=(h16)f[3];
    return r;
}
static __device__ __forceinline__ v8h cat8(v4h a, v4h b) {
    return __builtin_shufflevector(a, b, 0, 1, 2, 3, 4, 5, 6, 7);
}
// pack low-16 (f16 bits) of two Schraudolph f32 results into one h2
static __device__ __forceinline__ h2 pkperm(float t0, float t1) {
    unsigned r = __builtin_amdgcn_perm(__builtin_bit_cast(unsigned, t1),
                                       __builtin_bit_cast(unsigned, t0),
                                       0x05040100u);
    return __builtin_bit_cast(h2, r);
}

// ---------------------------------------------------------------------------
// Weight pack -> K=32 MFMA fragment order (v8h per lane).
// Slot map (self-consistent for A&B): slot 8g+i = channel 32u+4g+i (i<4),
//   32u+16+4g+(i-4) (i>=4).  wp[frag*64+lane], frag:
//   wq 0..23 (o=n,u) | whp 24..31 (o=cn,u) | wh1 32..47 (o=nf,u) |
//   wh2 48..63 (o=cn, u=0..3, K=128)
// ---------------------------------------------------------------------------
__global__ __launch_bounds__(256) void prep_pack(
    const float* __restrict__ Wqkv, const float* __restrict__ Wproj,
    const float* __restrict__ W1,   const float* __restrict__ W2,
    v8h* __restrict__ wp)
{
    int fid = blockIdx.x * 256 + threadIdx.x;   // 0..4095
    int lane = fid & 63;
    int lm = lane & 15, g4 = ((lane >> 4) & 3) * 4;
    int frag = fid >> 6;                        // 0..63
    const float* src; int o, u, K;
    if (frag < 24)      { o = frag >> 1;        u = frag & 1; K = 64;  src = Wqkv;  }
    else if (frag < 32) { o = (frag - 24) >> 1; u = frag & 1; K = 64;  src = Wproj; }
    else if (frag < 48) { o = (frag - 32) >> 1; u = frag & 1; K = 64;  src = W1;    }
    else                { o = (frag - 48) >> 2; u = frag & 3; K = 128; src = W2;    }
    const float* row = src + (size_t)(o*16 + lm) * K + u*32;
    v4f lo = *(const v4f*)(row + g4);
    v4f hi = *(const v4f*)(row + 16 + g4);
    v8h o8;
#pragma unroll
    for (int i = 0; i < 4; i++) { o8[i] = (h16)lo[i]; o8[4+i] = (h16)hi[i]; }
    wp[fid] = o8;
}

// ---------------------------------------------------------------------------
// qkv GEMM, n-split x4 (8192 waves), K=32 MFMA, packed weights.
// q pre-scaled by QSCALE. V stored SLOT-INTERLEAVED per 32-key supertile:
//   pos = supertile*512 + d*32 + 8g + half*4 + r   (matches PV A-slots)
// ---------------------------------------------------------------------------
__global__ __launch_bounds__(256) void qkv_gemm(
    const float* __restrict__ x, const v8h* __restrict__ wq,
    h16* __restrict__ q, h16* __restrict__ k, h16* __restrict__ vt)
{
    int tid = threadIdx.x;
    int lane = tid & 63, w = tid >> 6;
    int lm = lane & 15, g4 = (lane >> 4) * 4;
    int gw = blockIdx.x * 4 + w;            // 0..8191
    int tile = gw >> 2, ng = gw & 3;        // 3 n-values per wave
    int t0 = tile * 16;

    v4h af[4];
#pragma unroll
    for (int kt = 0; kt < 4; kt++)
        af[kt] = cvt4(*(const v4f*)(x + (size_t)(t0 + lm) * C_DIM + kt * 16 + g4));
    v8h a8[2];
    a8[0] = cat8(af[0], af[1]);
    a8[1] = cat8(af[2], af[3]);

    int b = t0 >> 11, tl = t0 & (T_SEQ - 1);
#pragma unroll
    for (int j = 0; j < 3; j++) {
        int n = ng * 3 + j;
        v4f acc = {0.f, 0.f, 0.f, 0.f};
        acc = MFMA32K(a8[0], wq[(n*2 + 0)*64 + lane], acc, 0, 0, 0);
        acc = MFMA32K(a8[1], wq[(n*2 + 1)*64 + lane], acc, 0, 0, 0);
        if (n < 4) {
            h16* qp = q + ((size_t)(b*N_H + n)*T_SEQ + tl + g4)*HD + lm;
#pragma unroll
            for (int r = 0; r < 4; r++) qp[r*HD] = (h16)(acc[r] * QSCALE);
        } else if (n < 8) {
            h16* kp = k + ((size_t)(b*N_H + (n-4))*T_SEQ + tl + g4)*HD + lm;
#pragma unroll
            for (int r = 0; r < 4; r++) kp[r*HD] = (h16)acc[r];
        } else {
            v4h pk;
#pragma unroll
            for (int r = 0; r < 4; r++) pk[r] = (h16)acc[r];
            int hv = (tl >> 4) & 1;
            *(v4h*)(vt + ((size_t)(b*N_H + (n-8))*(T_SEQ/32) + (tl >> 5))*512
                       + lm*32 + (lane >> 4)*8 + hv*4) = pk;
        }
    }
}

// ---------------------------------------------------------------------------
// Flash attention: NO-MAX softmax, Schraudolph fused into QK^T MFMA C-op,
// K-split x2, slot-interleaved V, PV via 16x16x32 (4 MFMA/kt instead of 8).
// Pointer-marching; loads-first + sched_barrier per kt.
// ---------------------------------------------------------------------------
__global__ __launch_bounds__(256, 8) void attn_mfma(
    const h16* __restrict__ q, const h16* __restrict__ k,
    const h16* __restrict__ vt, h16* __restrict__ a)
{
    int tid = threadIdx.x;
    int lane = tid & 63, w = tid >> 6;
    int lm = lane & 15, g4 = (lane >> 4) * 4;
    int bid = blockIdx.x;
    int W = (bid & 7) * 256 + (bid >> 3);     // XCD swizzle, bijective over 2048
    int bh = W >> 5;                          // 0..63
    int q64 = W & 31;                         // 64-query tile
    int q0 = q64 * 64 + (w & 1) * 32;
    int khalf = w >> 1;

    v4h qf0 = *(const v4h*)(q + ((size_t)bh*T_SEQ + q0      + lm)*HD + g4);
    v4h qf1 = *(const v4h*)(q + ((size_t)bh*T_SEQ + q0 + 16 + lm)*HD + g4);
    const h16* kpl = k  + ((size_t)bh*T_SEQ + khalf*1024 + lm)*HD + g4;
    const h16* vpl = vt + ((size_t)bh*(T_SEQ/32) + khalf*32)*512
                        + lm*32 + (lane >> 4)*8;

    v4f accA0={0,0,0,0}, accB0={0,0,0,0}, accA1={0,0,0,0}, accB1={0,0,0,0};
    float l0a = 0.f, l0b = 0.f, l1a = 0.f, l1b = 0.f;
    const v4f bvec = {BMAGIC, BMAGIC, BMAGIC, BMAGIC};

    for (int kt = 0; kt < 16; kt++) {
        // ---- issue ALL tile loads first (imm offsets off marching bases) ----
        v4h kf[4];
        v8h vf8[2];
#pragma unroll
        for (int m = 0; m < 4; m++)
            kf[m] = *(const v4h*)(kpl + m*256);
        vf8[0] = *(const v8h*)(vpl);
        vf8[1] = *(const v8h*)(vpl + 512);
        kpl += 1024; vpl += 1024;
        __builtin_amdgcn_sched_barrier(0);
        // ---- QK^T + softmax bits: t = BMAGIC + 1024*s from MFMA C-op ----
        v4h p0[4], p1[4];
#pragma unroll
        for (int m = 0; m < 4; m++) {
            v4f t0v = MFMA16(kf[m], qf0, bvec, 0, 0, 0);
            v4f t1v = MFMA16(kf[m], qf1, bvec, 0, 0, 0);
            h2 a0 = pkperm(t0v[0], t0v[1]);
            h2 b0 = pkperm(t0v[2], t0v[3]);
            h2 a1 = pkperm(t1v[0], t1v[1]);
            h2 b1 = pkperm(t1v[2], t1v[3]);
            l0a = fdot2p(a0, l0a); l0b = fdot2p(b0, l0b);
            l1a = fdot2p(a1, l1a); l1b = fdot2p(b1, l1b);
            p0[m] = __builtin_shufflevector(a0, b0, 0, 1, 2, 3);
            p1[m] = __builtin_shufflevector(a1, b1, 0, 1, 2, 3);
        }
        // ---- PV: K=32 shape, slot-consistent with V storage ----
        accA0 = MFMA32K(vf8[0], cat8(p0[0], p0[1]), accA0, 0, 0, 0);
        accA1 = MFMA32K(vf8[0], cat8(p1[0], p1[1]), accA1, 0, 0, 0);
        accB0 = MFMA32K(vf8[1], cat8(p0[2], p0[3]), accB0, 0, 0, 0);
        accB1 = MFMA32K(vf8[1], cat8(p1[2], p1[3]), accB1, 0, 0, 0);
    }

    // per-wave finalize
    float l0 = l0a + l0b, l1 = l1a + l1b;
    l0 += __shfl_xor(l0, 16, 64); l0 += __shfl_xor(l0, 32, 64);
    l1 += __shfl_xor(l1, 16, 64); l1 += __shfl_xor(l1, 32, 64);
    v4f acc0 = accA0 + accB0, acc1 = accA1 + accB1;

    // K-split merge via LDS: pure additive. Waves 2,3 publish.
    __shared__ float lds[2][64][13];
    if (w >= 2) {
        float* p = lds[w - 2][lane];
        p[0] = l0; p[1] = l1;
#pragma unroll
        for (int r = 0; r < 4; r++) { p[2 + r] = acc0[r]; p[6 + r] = acc1[r]; }
    }
    __syncthreads();
    if (w < 2) {
        const float* p = lds[w][lane];
        float inv0 = frcp(l0 + p[0]);
        float inv1 = frcp(l1 + p[1]);
        int b = bh >> 2, h = bh & 3;
        v4h o0, o1;
#pragma unroll
        for (int r = 0; r < 4; r++) {
            o0[r] = (h16)((acc0[r] + p[2 + r]) * inv0);
            o1[r] = (h16)((acc1[r] + p[6 + r]) * inv1);
        }
        *(v4h*)(a + ((size_t)(b*T_SEQ) + q0      + lm)*C_DIM + h*HD + g4) = o0;
        *(v4h*)(a + ((size_t)(b*T_SEQ) + q0 + 16 + lm)*C_DIM + h*HD + g4) = o1;
    }
}

// ---------------------------------------------------------------------------
// Fused tail, FFN split x2, K=32 MFMA, packed weights, loads-first.
// ---------------------------------------------------------------------------
__global__ __launch_bounds__(256) void tail_fused(
    const h16* __restrict__ a, const float* __restrict__ x,
    const v8h* __restrict__ wp,
    const float* __restrict__ b1, const float* __restrict__ b2,
    const float* __restrict__ g1, const float* __restrict__ be1,
    const float* __restrict__ g2, const float* __restrict__ be2,
    float* __restrict__ out)
{
    int tid = threadIdx.x;
    int lane = tid & 63, w = tid >> 6;
    int lm = lane & 15, g4 = (lane >> 4) * 4;
    int pair = w >> 1;                 // token tile in block
    int half = w & 1;                  // ffn half
    int t0 = (blockIdx.x * 2 + pair) * 16;

    const v8h* whp = wp + 24*64;
    const v8h* wh1 = wp + 32*64;
    const v8h* wh2 = wp + 48*64;

    v4h af[4];
#pragma unroll
    for (int kt = 0; kt < 4; kt++)
        af[kt] = *(const v4h*)(a + (size_t)(t0 + lm)*C_DIM + kt*16 + g4);
    v8h a8[2];
    a8[0] = cat8(af[0], af[1]);
    a8[1] = cat8(af[2], af[3]);

    // ---- proj + residual + LN1 (both halves compute; cheap) ----
    float rvn[4][4];
    v8h x8[2];
    {
        v8h wf[8];
#pragma unroll
        for (int f = 0; f < 8; f++) wf[f] = whp[f*64 + lane];
        __builtin_amdgcn_sched_barrier(0);
        v4f rv[4];
#pragma unroll
        for (int cn = 0; cn < 4; cn++) {
            v4f acc = {0.f, 0.f, 0.f, 0.f};
            acc = MFMA32K(wf[cn*2 + 0], a8[0], acc, 0, 0, 0);
            acc = MFMA32K(wf[cn*2 + 1], a8[1], acc, 0, 0, 0);
            v4f xr = *(const v4f*)(x + (size_t)(t0 + lm)*C_DIM + cn*16 + g4);
            rv[cn] = acc + xr;
        }
        float s = 0.f;
#pragma unroll
        for (int cn = 0; cn < 4; cn++)
#pragma unroll
            for (int i = 0; i < 4; i++) s += rv[cn][i];
        s += __shfl_xor(s, 16, 64); s += __shfl_xor(s, 32, 64);
        float mu = s * (1.f/64.f);
        float qs = 0.f;
#pragma unroll
        for (int cn = 0; cn < 4; cn++)
#pragma unroll
            for (int i = 0; i < 4; i++) { float d = rv[cn][i] - mu; qs += d*d; }
        qs += __shfl_xor(qs, 16, 64); qs += __shfl_xor(qs, 32, 64);
        float is = frsq(qs * (1.f/64.f) + EPS_LN);
        v4h x1t[4];
#pragma unroll
        for (int cn = 0; cn < 4; cn++) {
            v4f g1v = *(const v4f*)(g1 + cn*16 + g4);
            v4f bev = *(const v4f*)(be1 + cn*16 + g4);
#pragma unroll
            for (int i = 0; i < 4; i++) {
                float vl = (rv[cn][i] - mu) * is * g1v[i] + bev[i];
                rvn[cn][i] = vl;
                x1t[cn][i] = (h16)vl;
            }
        }
        x8[0] = cat8(x1t[0], x1t[1]);
        x8[1] = cat8(x1t[2], x1t[3]);
    }
    __builtin_amdgcn_sched_barrier(0);

    // ---- FFN1 half + ReLU (4 of 8 nf groups) ----
    v8h h8[2];
    {
        v8h wf[8];
#pragma unroll
        for (int j = 0; j < 4; j++) {
            int nf = half * 4 + j;
            wf[j*2]     = wh1[(nf*2 + 0)*64 + lane];
            wf[j*2 + 1] = wh1[(nf*2 + 1)*64 + lane];
        }
        __builtin_amdgcn_sched_barrier(0);
        v4h ht[4];
#pragma unroll
        for (int j = 0; j < 4; j++) {
            int nf = half * 4 + j;
            v4f acc = {0.f, 0.f, 0.f, 0.f};
            acc = MFMA32K(wf[j*2],     x8[0], acc, 0, 0, 0);
            acc = MFMA32K(wf[j*2 + 1], x8[1], acc, 0, 0, 0);
            v4f b1v = *(const v4f*)(b1 + nf*16 + g4);
#pragma unroll
            for (int i = 0; i < 4; i++) ht[j][i] = (h16)fmaxf(acc[i] + b1v[i], 0.f);
        }
        h8[0] = cat8(ht[0], ht[1]);
        h8[1] = cat8(ht[2], ht[3]);
    }
    __builtin_amdgcn_sched_barrier(0);

    // ---- FFN2 partial over this half's 64 hidden units ----
    float yp[4][4];
    {
        v8h wf[8];
#pragma unroll
        for (int cn = 0; cn < 4; cn++)
#pragma unroll
            for (int v = 0; v < 2; v++)
                wf[cn*2 + v] = wh2[(cn*4 + 2*half + v)*64 + lane];
        __builtin_amdgcn_sched_barrier(0);
#pragma unroll
        for (int cn = 0; cn < 4; cn++) {
            v4f acc = {0.f, 0.f, 0.f, 0.f};
            acc = MFMA32K(wf[cn*2],     h8[0], acc, 0, 0, 0);
            acc = MFMA32K(wf[cn*2 + 1], h8[1], acc, 0, 0, 0);
#pragma unroll
            for (int i = 0; i < 4; i++) yp[cn][i] = acc[i];
        }
    }

    // ---- merge halves via LDS; half 0 finishes ----
    __shared__ float lds[2][64][17];
    if (half == 1) {
        float* p = lds[pair][lane];
#pragma unroll
        for (int cn = 0; cn < 4; cn++)
#pragma unroll
            for (int i = 0; i < 4; i++) p[cn*4 + i] = yp[cn][i];
    }
    __syncthreads();
    if (half == 0) {
        const float* p = lds[pair][lane];
        float yv[4][4];
#pragma unroll
        for (int cn = 0; cn < 4; cn++) {
            v4f b2v = *(const v4f*)(b2 + cn*16 + g4);
#pragma unroll
            for (int i = 0; i < 4; i++)
                yv[cn][i] = yp[cn][i] + p[cn*4 + i] + b2v[i] + rvn[cn][i];
        }
        float s2 = 0.f;
#pragma unroll
        for (int cn = 0; cn < 4; cn++)
#pragma unroll
            for (int i = 0; i < 4; i++) s2 += yv[cn][i];
        s2 += __shfl_xor(s2, 16, 64); s2 += __shfl_xor(s2, 32, 64);
        float mu2 = s2 * (1.f/64.f);
        float qs2 = 0.f;
#pragma unroll
        for (int cn = 0; cn < 4; cn++)
#pragma unroll
            for (int i = 0; i < 4; i++) { float d = yv[cn][i] - mu2; qs2 += d*d; }
        qs2 += __shfl_xor(qs2, 16, 64); qs2 += __shfl_xor(qs2, 32, 64);
        float is2 = frsq(qs2 * (1.f/64.f) + EPS_LN);
#pragma unroll
        for (int cn = 0; cn < 4; cn++) {
            v4f g2v = *(const v4f*)(g2 + cn*16 + g4);
            v4f bev = *(const v4f*)(be2 + cn*16 + g4);
            v4f o;
#pragma unroll
            for (int i = 0; i < 4; i++) o[i] = (yv[cn][i] - mu2) * is2 * g2v[i] + bev[i];
            *(v4f*)(out + (size_t)(t0 + lm)*C_DIM + cn*16 + g4) = o;
        }
    }
}

// ---------------------------------------------------------------------------
extern "C" void kernel_launch(void* const* d_in, const int* in_sizes, int n_in,
                              void* d_out, int out_size, void* d_ws, size_t ws_size,
                              hipStream_t stream)
{
    const float* x     = (const float*)d_in[0];
    const float* Wqkv  = (const float*)d_in[1];
    const float* Wproj = (const float*)d_in[2];
    const float* W1    = (const float*)d_in[3];
    const float* b1    = (const float*)d_in[4];
    const float* W2    = (const float*)d_in[5];
    const float* b2    = (const float*)d_in[6];
    const float* g1    = (const float*)d_in[7];
    const float* be1   = (const float*)d_in[8];
    const float* g2    = (const float*)d_in[9];
    const float* be2   = (const float*)d_in[10];
    float* out = (float*)d_out;

    const size_t perQ = (size_t)BATCH * N_H * T_SEQ * HD;   // 2M elements
    h16* q   = (h16*)d_ws;
    h16* kk  = q  + perQ;
    h16* vt  = kk + perQ;
    h16* a   = vt + perQ;
    v8h* wp  = (v8h*)(a + (size_t)NTOK * C_DIM);            // 4096 v8h, 64 KB

    prep_pack  <<<16,   256, 0, stream>>>(Wqkv, Wproj, W1, W2, wp);
    qkv_gemm   <<<2048, 256, 0, stream>>>(x, wp, q, kk, vt);
    attn_mfma  <<<2048, 256, 0, stream>>>(q, kk, vt, a);
    tail_fused <<<1024, 256, 0, stream>>>(a, x, wp, b1, b2,
                                          g1, be1, g2, be2, out);
}

// Round 18
// 69.003 us; speedup vs baseline: 1.0897x; 1.0897x over previous
//
#include <hip/hip_runtime.h>
#include <hip/hip_bf16.h>
#include <math.h>

typedef _Float16 h16;
typedef h16   v4h __attribute__((ext_vector_type(4)));
typedef h16   h2  __attribute__((ext_vector_type(2)));
typedef float v4f __attribute__((ext_vector_type(4)));

#define T_SEQ 2048
#define BATCH 16
#define NTOK  (BATCH * T_SEQ)
#define C_DIM 64
#define N_H   4
#define HD    16
#define FF    128
#define EPS_LN 1e-5f
#define MFMA16 __builtin_amdgcn_mfma_f32_16x16x16f16
// q pre-scale: hd^-0.5 * log2(e) * 1024 (Schraudolph FMA fused into QK^T MFMA C-op)
#define QSCALE (0.25f * 1.44269504089f * 1024.0f)
#define BMAGIC (12582912.0f + 15316.0f)   // 1.5*2^23 + (15360-44)

static __device__ __forceinline__ float frcp(float x) {
#if __has_builtin(__builtin_amdgcn_rcpf)
    return __builtin_amdgcn_rcpf(x);
#else
    return 1.0f / x;
#endif
}
static __device__ __forceinline__ float frsq(float x) {
#if __has_builtin(__builtin_amdgcn_rsqf)
    return __builtin_amdgcn_rsqf(x);
#else
    return rsqrtf(x);
#endif
}
static __device__ __forceinline__ float fdot2p(h2 a, float acc) {
#if __has_builtin(__builtin_amdgcn_fdot2)
    const h2 one2 = {(h16)1.0f, (h16)1.0f};
    return __builtin_amdgcn_fdot2(a, one2, acc, false);
#else
    return acc + (float)a[0] + (float)a[1];
#endif
}
static __device__ __forceinline__ v4h cvt4(v4f f) {
    v4h r; r[0]=(h16)f[0]; r[1]=(h16)f[1]; r[2]=(h16)f[2]; r[3]=(h16)f[3];
    return r;
}
// pack low-16 (f16 bits) of two Schraudolph f32 results into one h2
static __device__ __forceinline__ h2 pkperm(float t0, float t1) {
    unsigned r = __builtin_amdgcn_perm(__builtin_bit_cast(unsigned, t1),
                                       __builtin_bit_cast(unsigned, t0),
                                       0x05040100u);
    return __builtin_bit_cast(h2, r);
}

// ---------------------------------------------------------------------------
// Weight pack: all four weight matrices -> f16 MFMA-fragment order, once.
// wp[f][lane] (v4h), element i = W[(o*16+lm)*K + kt*16+g4+i].
// Segments: wq [0,3072) | whp [3072,4096) | wh1 [4096,6144) | wh2 [6144,8192)
// ---------------------------------------------------------------------------
__global__ __launch_bounds__(256) void prep_pack(
    const float* __restrict__ Wqkv, const float* __restrict__ Wproj,
    const float* __restrict__ W1,   const float* __restrict__ W2,
    v4h* __restrict__ wp)
{
    int fid = blockIdx.x * 256 + threadIdx.x;   // 0..8191
    int lane = fid & 63;
    int lm = lane & 15, g4 = ((lane >> 4) & 3) * 4;
    int frag = fid >> 6;
    const float* src; int o, kt, K;
    if (fid < 3072)      { int f = frag;      o = f >> 2; kt = f & 3; K = 64;  src = Wqkv;  }
    else if (fid < 4096) { int f = frag - 48; o = f >> 2; kt = f & 3; K = 64;  src = Wproj; }
    else if (fid < 6144) { int f = frag - 64; o = f >> 2; kt = f & 3; K = 64;  src = W1;    }
    else                 { int f = frag - 96; o = f >> 3; kt = f & 7; K = 128; src = W2;    }
    v4f v = *(const v4f*)(src + (o*16 + lm)*K + kt*16 + g4);
    wp[fid] = cvt4(v);
}

// ---------------------------------------------------------------------------
// qkv GEMM: 1 block = 1 token-tile (coalesced 4KB x load -> LDS f16),
// 4 waves = n-split x4 over 12 output columns. Packed weights.
// q pre-scaled by QSCALE. V stored TILED: [bh][key_tile][d16][key16].
// ---------------------------------------------------------------------------
__global__ __launch_bounds__(256) void qkv_gemm(
    const float* __restrict__ x, const v4h* __restrict__ wq,
    h16* __restrict__ q, h16* __restrict__ k, h16* __restrict__ vt)
{
    int tid = threadIdx.x;
    int lane = tid & 63, w = tid >> 6;
    int lm = lane & 15, g4 = (lane >> 4) * 4;
    int tile = blockIdx.x;                  // 0..2047
    int t0 = tile * 16;
    int ng = w;                             // 3 n-values per wave

    // coalesced x load: 256 threads x 16B = the tile's contiguous 4KB
    __shared__ h16 xs[16][72];              // +8 f16 pad per row (bank spread)
    {
        v4f v = *(const v4f*)(x + (size_t)t0 * C_DIM + tid * 4);
        int r = tid >> 4;                   // row (token within tile)
        int c = (tid & 15) * 4;             // col (channel)
        *(v4h*)&xs[r][c] = cvt4(v);
    }
    __syncthreads();

    v4h af[4];
#pragma unroll
    for (int kt = 0; kt < 4; kt++)
        af[kt] = *(const v4h*)&xs[lm][kt*16 + g4];

    int b = t0 >> 11, tl = t0 & (T_SEQ - 1);
#pragma unroll
    for (int j = 0; j < 3; j++) {
        int n = ng * 3 + j;
        v4f acc = {0.f, 0.f, 0.f, 0.f};
#pragma unroll
        for (int kt = 0; kt < 4; kt++)
            acc = MFMA16(af[kt], wq[(n*4 + kt)*64 + lane], acc, 0, 0, 0);
        if (n < 4) {
            h16* qp = q + ((size_t)(b*N_H + n)*T_SEQ + tl + g4)*HD + lm;
#pragma unroll
            for (int r = 0; r < 4; r++) qp[r*HD] = (h16)(acc[r] * QSCALE);
        } else if (n < 8) {
            h16* kp = k + ((size_t)(b*N_H + (n-4))*T_SEQ + tl + g4)*HD + lm;
#pragma unroll
            for (int r = 0; r < 4; r++) kp[r*HD] = (h16)acc[r];
        } else {
            v4h pk;
#pragma unroll
            for (int r = 0; r < 4; r++) pk[r] = (h16)acc[r];
            *(v4h*)(vt + ((size_t)(b*N_H + (n-8))*(T_SEQ/16) + (tl >> 4))*256
                       + lm*16 + g4) = pk;
        }
    }
}

// ---------------------------------------------------------------------------
// Flash attention: NO-MAX softmax, Schraudolph fused into QK^T MFMA C-op,
// K-split x2, tiled V, pointer-marching, 1-deep K pipeline (kfA/kfB rotation,
// sched_barrier fences prevent the scheduler sinking the prefetch).
// ---------------------------------------------------------------------------
__global__ __launch_bounds__(256, 6) void attn_mfma(
    const h16* __restrict__ q, const h16* __restrict__ k,
    const h16* __restrict__ vt, h16* __restrict__ a)
{
    int tid = threadIdx.x;
    int lane = tid & 63, w = tid >> 6;
    int lm = lane & 15, g4 = (lane >> 4) * 4;
    int bid = blockIdx.x;
    int W = (bid & 7) * 256 + (bid >> 3);     // XCD swizzle, bijective over 2048
    int bh = W >> 5;                          // 0..63
    int q64 = W & 31;                         // 64-query tile
    int q0 = q64 * 64 + (w & 1) * 32;
    int khalf = w >> 1;

    v4h qf0 = *(const v4h*)(q + ((size_t)bh*T_SEQ + q0      + lm)*HD + g4);
    v4h qf1 = *(const v4h*)(q + ((size_t)bh*T_SEQ + q0 + 16 + lm)*HD + g4);
    const h16* kpl = k  + ((size_t)bh*T_SEQ + khalf*1024 + lm)*HD + g4;
    const h16* vpl = vt + ((size_t)bh*(T_SEQ/16) + khalf*64)*256 + lm*16 + g4;

    v4f accA0={0,0,0,0}, accB0={0,0,0,0}, accA1={0,0,0,0}, accB1={0,0,0,0};
    float l0a = 0.f, l0b = 0.f, l1a = 0.f, l1b = 0.f;
    const v4f bvec = {BMAGIC, BMAGIC, BMAGIC, BMAGIC};

    // pipeline prologue: K tile 0 in kfA
    v4h kfA[4], kfB[4];
#pragma unroll
    for (int m = 0; m < 4; m++) kfA[m] = *(const v4h*)(kpl + m*256);
    kpl += 1024;

#define ATTN_BODY(KCUR, KNXT)                                                 \
    {                                                                         \
        v4h vf[4];                                                            \
        _Pragma("unroll")                                                     \
        for (int m = 0; m < 4; m++) vf[m] = *(const v4h*)(vpl + m*256);       \
        _Pragma("unroll")                                                     \
        for (int m = 0; m < 4; m++) KNXT[m] = *(const v4h*)(kpl + m*256);     \
        vpl += 1024; kpl += 1024;                                             \
        __builtin_amdgcn_sched_barrier(0);                                    \
        _Pragma("unroll")                                                     \
        for (int m = 0; m < 4; m++) {                                         \
            v4f t0v = MFMA16(KCUR[m], qf0, bvec, 0, 0, 0);                    \
            v4f t1v = MFMA16(KCUR[m], qf1, bvec, 0, 0, 0);                    \
            h2 a0 = pkperm(t0v[0], t0v[1]);                                   \
            h2 b0 = pkperm(t0v[2], t0v[3]);                                   \
            h2 a1 = pkperm(t1v[0], t1v[1]);                                   \
            h2 b1 = pkperm(t1v[2], t1v[3]);                                   \
            l0a = fdot2p(a0, l0a); l0b = fdot2p(b0, l0b);                     \
            l1a = fdot2p(a1, l1a); l1b = fdot2p(b1, l1b);                     \
            v4h p0 = __builtin_shufflevector(a0, b0, 0, 1, 2, 3);             \
            v4h p1 = __builtin_shufflevector(a1, b1, 0, 1, 2, 3);             \
            if (m & 1) { accB0 = MFMA16(vf[m], p0, accB0, 0,0,0);             \
                         accB1 = MFMA16(vf[m], p1, accB1, 0,0,0); }           \
            else       { accA0 = MFMA16(vf[m], p0, accA0, 0,0,0);             \
                         accA1 = MFMA16(vf[m], p1, accA1, 0,0,0); }           \
        }                                                                     \
        __builtin_amdgcn_sched_barrier(0);                                    \
    }

    for (int kt = 0; kt < 16; kt += 2) {
        ATTN_BODY(kfA, kfB)      // compute tile kt,   prefetch kt+1
        ATTN_BODY(kfB, kfA)      // compute tile kt+1, prefetch kt+2
    }
#undef ATTN_BODY

    // per-wave finalize
    float l0 = l0a + l0b, l1 = l1a + l1b;
    l0 += __shfl_xor(l0, 16, 64); l0 += __shfl_xor(l0, 32, 64);
    l1 += __shfl_xor(l1, 16, 64); l1 += __shfl_xor(l1, 32, 64);
    v4f acc0 = accA0 + accB0, acc1 = accA1 + accB1;

    // K-split merge via LDS: pure additive. Waves 2,3 publish.
    __shared__ float lds[2][64][13];
    if (w >= 2) {
        float* p = lds[w - 2][lane];
        p[0] = l0; p[1] = l1;
#pragma unroll
        for (int r = 0; r < 4; r++) { p[2 + r] = acc0[r]; p[6 + r] = acc1[r]; }
    }
    __syncthreads();
    if (w < 2) {
        const float* p = lds[w][lane];
        float inv0 = frcp(l0 + p[0]);
        float inv1 = frcp(l1 + p[1]);
        int b = bh >> 2, h = bh & 3;
        v4h o0, o1;
#pragma unroll
        for (int r = 0; r < 4; r++) {
            o0[r] = (h16)((acc0[r] + p[2 + r]) * inv0);
            o1[r] = (h16)((acc1[r] + p[6 + r]) * inv1);
        }
        *(v4h*)(a + ((size_t)(b*T_SEQ) + q0      + lm)*C_DIM + h*HD + g4) = o0;
        *(v4h*)(a + ((size_t)(b*T_SEQ) + q0 + 16 + lm)*C_DIM + h*HD + g4) = o1;
    }
}

// ---------------------------------------------------------------------------
// Fused tail, FFN split x2, packed weights, loads-first per section.
// ---------------------------------------------------------------------------
__global__ __launch_bounds__(256) void tail_fused(
    const h16* __restrict__ a, const float* __restrict__ x,
    const v4h* __restrict__ wp,
    const float* __restrict__ b1, const float* __restrict__ b2,
    const float* __restrict__ g1, const float* __restrict__ be1,
    const float* __restrict__ g2, const float* __restrict__ be2,
    float* __restrict__ out)
{
    int tid = threadIdx.x;
    int lane = tid & 63, w = tid >> 6;
    int lm = lane & 15, g4 = (lane >> 4) * 4;
    int pair = w >> 1;                 // token tile in block
    int half = w & 1;                  // ffn half
    int t0 = (blockIdx.x * 2 + pair) * 16;

    const v4h* whp = wp + 3072;
    const v4h* wh1 = wp + 4096;
    const v4h* wh2 = wp + 6144;

    v4h af[4];
#pragma unroll
    for (int kt = 0; kt < 4; kt++)
        af[kt] = *(const v4h*)(a + (size_t)(t0 + lm)*C_DIM + kt*16 + g4);

    // ---- proj + residual + LN1 (both halves compute; cheap) ----
    float rvn[4][4];
    v4h x1t[4];
    {
        v4h wf[16];
#pragma unroll
        for (int f = 0; f < 16; f++) wf[f] = whp[f*64 + lane];
        __builtin_amdgcn_sched_barrier(0);
        v4f rv[4];
#pragma unroll
        for (int cn = 0; cn < 4; cn++) {
            v4f acc = {0.f, 0.f, 0.f, 0.f};
#pragma unroll
            for (int kt = 0; kt < 4; kt++)
                acc = MFMA16(wf[cn*4 + kt], af[kt], acc, 0, 0, 0);
            v4f xr = *(const v4f*)(x + (size_t)(t0 + lm)*C_DIM + cn*16 + g4);
            rv[cn] = acc + xr;
        }
        float s = 0.f;
#pragma unroll
        for (int cn = 0; cn < 4; cn++)
#pragma unroll
            for (int i = 0; i < 4; i++) s += rv[cn][i];
        s += __shfl_xor(s, 16, 64); s += __shfl_xor(s, 32, 64);
        float mu = s * (1.f/64.f);
        float qs = 0.f;
#pragma unroll
        for (int cn = 0; cn < 4; cn++)
#pragma unroll
            for (int i = 0; i < 4; i++) { float d = rv[cn][i] - mu; qs += d*d; }
        qs += __shfl_xor(qs, 16, 64); qs += __shfl_xor(qs, 32, 64);
        float is = frsq(qs * (1.f/64.f) + EPS_LN);
#pragma unroll
        for (int cn = 0; cn < 4; cn++) {
            v4f g1v = *(const v4f*)(g1 + cn*16 + g4);
            v4f bev = *(const v4f*)(be1 + cn*16 + g4);
#pragma unroll
            for (int i = 0; i < 4; i++) {
                float vl = (rv[cn][i] - mu) * is * g1v[i] + bev[i];
                rvn[cn][i] = vl;
                x1t[cn][i] = (h16)vl;
            }
        }
    }
    __builtin_amdgcn_sched_barrier(0);

    // ---- FFN1 half + ReLU (4 of 8 nf groups) ----
    v4h ht[4];
    {
        v4h wf[16];
#pragma unroll
        for (int f = 0; f < 16; f++) wf[f] = wh1[(half*16 + f)*64 + lane];
        __builtin_amdgcn_sched_barrier(0);
#pragma unroll
        for (int j = 0; j < 4; j++) {
            int nf = half * 4 + j;
            v4f acc = {0.f, 0.f, 0.f, 0.f};
#pragma unroll
            for (int kt = 0; kt < 4; kt++)
                acc = MFMA16(wf[j*4 + kt], x1t[kt], acc, 0, 0, 0);
            v4f b1v = *(const v4f*)(b1 + nf*16 + g4);
#pragma unroll
            for (int i = 0; i < 4; i++) ht[j][i] = (h16)fmaxf(acc[i] + b1v[i], 0.f);
        }
    }
    __builtin_amdgcn_sched_barrier(0);

    // ---- FFN2 partial over this half's 64 hidden units ----
    float yp[4][4];
    {
        v4h wf[16];
#pragma unroll
        for (int cn = 0; cn < 4; cn++)
#pragma unroll
            for (int j = 0; j < 4; j++)
                wf[cn*4 + j] = wh2[(cn*8 + half*4 + j)*64 + lane];
        __builtin_amdgcn_sched_barrier(0);
#pragma unroll
        for (int cn = 0; cn < 4; cn++) {
            v4f acc = {0.f, 0.f, 0.f, 0.f};
#pragma unroll
            for (int j = 0; j < 4; j++)
                acc = MFMA16(wf[cn*4 + j], ht[j], acc, 0, 0, 0);
#pragma unroll
            for (int i = 0; i < 4; i++) yp[cn][i] = acc[i];
        }
    }

    // ---- merge halves via LDS; half 0 finishes ----
    __shared__ float lds[2][64][17];
    if (half == 1) {
        float* p = lds[pair][lane];
#pragma unroll
        for (int cn = 0; cn < 4; cn++)
#pragma unroll
            for (int i = 0; i < 4; i++) p[cn*4 + i] = yp[cn][i];
    }
    __syncthreads();
    if (half == 0) {
        const float* p = lds[pair][lane];
        float yv[4][4];
#pragma unroll
        for (int cn = 0; cn < 4; cn++) {
            v4f b2v = *(const v4f*)(b2 + cn*16 + g4);
#pragma unroll
            for (int i = 0; i < 4; i++)
                yv[cn][i] = yp[cn][i] + p[cn*4 + i] + b2v[i] + rvn[cn][i];
        }
        float s2 = 0.f;
#pragma unroll
        for (int cn = 0; cn < 4; cn++)
#pragma unroll
            for (int i = 0; i < 4; i++) s2 += yv[cn][i];
        s2 += __shfl_xor(s2, 16, 64); s2 += __shfl_xor(s2, 32, 64);
        float mu2 = s2 * (1.f/64.f);
        float qs2 = 0.f;
#pragma unroll
        for (int cn = 0; cn < 4; cn++)
#pragma unroll
            for (int i = 0; i < 4; i++) { float d = yv[cn][i] - mu2; qs2 += d*d; }
        qs2 += __shfl_xor(qs2, 16, 64); qs2 += __shfl_xor(qs2, 32, 64);
        float is2 = frsq(qs2 * (1.f/64.f) + EPS_LN);
#pragma unroll
        for (int cn = 0; cn < 4; cn++) {
            v4f g2v = *(const v4f*)(g2 + cn*16 + g4);
            v4f bev = *(const v4f*)(be2 + cn*16 + g4);
            v4f o;
#pragma unroll
            for (int i = 0; i < 4; i++) o[i] = (yv[cn][i] - mu2) * is2 * g2v[i] + bev[i];
            *(v4f*)(out + (size_t)(t0 + lm)*C_DIM + cn*16 + g4) = o;
        }
    }
}

// ---------------------------------------------------------------------------
extern "C" void kernel_launch(void* const* d_in, const int* in_sizes, int n_in,
                              void* d_out, int out_size, void* d_ws, size_t ws_size,
                              hipStream_t stream)
{
    const float* x     = (const float*)d_in[0];
    const float* Wqkv  = (const float*)d_in[1];
    const float* Wproj = (const float*)d_in[2];
    const float* W1    = (const float*)d_in[3];
    const float* b1    = (const float*)d_in[4];
    const float* W2    = (const float*)d_in[5];
    const float* b2    = (const float*)d_in[6];
    const float* g1    = (const float*)d_in[7];
    const float* be1   = (const float*)d_in[8];
    const float* g2    = (const float*)d_in[9];
    const float* be2   = (const float*)d_in[10];
    float* out = (float*)d_out;

    const size_t perQ = (size_t)BATCH * N_H * T_SEQ * HD;   // 2M elements
    h16* q   = (h16*)d_ws;
    h16* kk  = q  + perQ;
    h16* vt  = kk + perQ;
    h16* a   = vt + perQ;
    v4h* wp  = (v4h*)(a + (size_t)NTOK * C_DIM);            // 8192 frags, 64 KB

    prep_pack  <<<32,   256, 0, stream>>>(Wqkv, Wproj, W1, W2, wp);
    qkv_gemm   <<<2048, 256, 0, stream>>>(x, wp, q, kk, vt);
    attn_mfma  <<<2048, 256, 0, stream>>>(q, kk, vt, a);
    tail_fused <<<1024, 256, 0, stream>>>(a, x, wp, b1, b2,
                                          g1, be1, g2, be2, out);
}

// Round 19
// 63.773 us; speedup vs baseline: 1.1791x; 1.0820x over previous
//
#include <hip/hip_runtime.h>
#include <hip/hip_bf16.h>
#include <math.h>

typedef _Float16 h16;
typedef h16   v4h __attribute__((ext_vector_type(4)));
typedef h16   h2  __attribute__((ext_vector_type(2)));
typedef float v4f __attribute__((ext_vector_type(4)));

#define T_SEQ 2048
#define BATCH 16
#define NTOK  (BATCH * T_SEQ)
#define C_DIM 64
#define N_H   4
#define HD    16
#define FF    128
#define EPS_LN 1e-5f
#define MFMA16 __builtin_amdgcn_mfma_f32_16x16x16f16
// q pre-scale: hd^-0.5 * log2(e) * 1024 (Schraudolph FMA fused into QK^T MFMA C-op)
#define QSCALE (0.25f * 1.44269504089f * 1024.0f)
#define BMAGIC (12582912.0f + 15316.0f)   // 1.5*2^23 + (15360-44)

static __device__ __forceinline__ float frcp(float x) {
#if __has_builtin(__builtin_amdgcn_rcpf)
    return __builtin_amdgcn_rcpf(x);
#else
    return 1.0f / x;
#endif
}
static __device__ __forceinline__ float frsq(float x) {
#if __has_builtin(__builtin_amdgcn_rsqf)
    return __builtin_amdgcn_rsqf(x);
#else
    return rsqrtf(x);
#endif
}
static __device__ __forceinline__ float fdot2p(h2 a, float acc) {
#if __has_builtin(__builtin_amdgcn_fdot2)
    const h2 one2 = {(h16)1.0f, (h16)1.0f};
    return __builtin_amdgcn_fdot2(a, one2, acc, false);
#else
    return acc + (float)a[0] + (float)a[1];
#endif
}
static __device__ __forceinline__ v4h cvt4(v4f f) {
    v4h r; r[0]=(h16)f[0]; r[1]=(h16)f[1]; r[2]=(h16)f[2]; r[3]=(h16)f[3];
    return r;
}
// pack low-16 (f16 bits) of two Schraudolph f32 results into one h2
static __device__ __forceinline__ h2 pkperm(float t0, float t1) {
    unsigned r = __builtin_amdgcn_perm(__builtin_bit_cast(unsigned, t1),
                                       __builtin_bit_cast(unsigned, t0),
                                       0x05040100u);
    return __builtin_bit_cast(h2, r);
}

// ---------------------------------------------------------------------------
// Weight pack: all four weight matrices -> f16 MFMA-fragment order, once.
// wp[f][lane] (v4h), element i = W[(o*16+lm)*K + kt*16+g4+i].
// Segments: wq [0,3072) | whp [3072,4096) | wh1 [4096,6144) | wh2 [6144,8192)
// ---------------------------------------------------------------------------
__global__ __launch_bounds__(256) void prep_pack(
    const float* __restrict__ Wqkv, const float* __restrict__ Wproj,
    const float* __restrict__ W1,   const float* __restrict__ W2,
    v4h* __restrict__ wp)
{
    int fid = blockIdx.x * 256 + threadIdx.x;   // 0..8191
    int lane = fid & 63;
    int lm = lane & 15, g4 = ((lane >> 4) & 3) * 4;
    int frag = fid >> 6;
    const float* src; int o, kt, K;
    if (fid < 3072)      { int f = frag;      o = f >> 2; kt = f & 3; K = 64;  src = Wqkv;  }
    else if (fid < 4096) { int f = frag - 48; o = f >> 2; kt = f & 3; K = 64;  src = Wproj; }
    else if (fid < 6144) { int f = frag - 64; o = f >> 2; kt = f & 3; K = 64;  src = W1;    }
    else                 { int f = frag - 96; o = f >> 3; kt = f & 7; K = 128; src = W2;    }
    v4f v = *(const v4f*)(src + (o*16 + lm)*K + kt*16 + g4);
    wp[fid] = cvt4(v);
}

// ---------------------------------------------------------------------------
// qkv GEMM: 1 block = 1 token-tile (coalesced 4KB x load -> LDS f16),
// 4 waves = n-split x4 over 12 output columns. Packed weights.
// q pre-scaled by QSCALE. V stored TILED: [bh][key_tile][d16][key16].
// ---------------------------------------------------------------------------
__global__ __launch_bounds__(256) void qkv_gemm(
    const float* __restrict__ x, const v4h* __restrict__ wq,
    h16* __restrict__ q, h16* __restrict__ k, h16* __restrict__ vt)
{
    int tid = threadIdx.x;
    int lane = tid & 63, w = tid >> 6;
    int lm = lane & 15, g4 = (lane >> 4) * 4;
    int tile = blockIdx.x;                  // 0..2047
    int t0 = tile * 16;
    int ng = w;                             // 3 n-values per wave

    // coalesced x load: 256 threads x 16B = the tile's contiguous 4KB
    __shared__ h16 xs[16][72];              // +8 f16 pad per row (bank spread)
    {
        v4f v = *(const v4f*)(x + (size_t)t0 * C_DIM + tid * 4);
        int r = tid >> 4;                   // row (token within tile)
        int c = (tid & 15) * 4;             // col (channel)
        *(v4h*)&xs[r][c] = cvt4(v);
    }
    __syncthreads();

    v4h af[4];
#pragma unroll
    for (int kt = 0; kt < 4; kt++)
        af[kt] = *(const v4h*)&xs[lm][kt*16 + g4];

    int b = t0 >> 11, tl = t0 & (T_SEQ - 1);
#pragma unroll
    for (int j = 0; j < 3; j++) {
        int n = ng * 3 + j;
        v4f acc = {0.f, 0.f, 0.f, 0.f};
#pragma unroll
        for (int kt = 0; kt < 4; kt++)
            acc = MFMA16(af[kt], wq[(n*4 + kt)*64 + lane], acc, 0, 0, 0);
        if (n < 4) {
            h16* qp = q + ((size_t)(b*N_H + n)*T_SEQ + tl + g4)*HD + lm;
#pragma unroll
            for (int r = 0; r < 4; r++) qp[r*HD] = (h16)(acc[r] * QSCALE);
        } else if (n < 8) {
            h16* kp = k + ((size_t)(b*N_H + (n-4))*T_SEQ + tl + g4)*HD + lm;
#pragma unroll
            for (int r = 0; r < 4; r++) kp[r*HD] = (h16)acc[r];
        } else {
            v4h pk;
#pragma unroll
            for (int r = 0; r < 4; r++) pk[r] = (h16)acc[r];
            *(v4h*)(vt + ((size_t)(b*N_H + (n-8))*(T_SEQ/16) + (tl >> 4))*256
                       + lm*16 + g4) = pk;
        }
    }
}

// ---------------------------------------------------------------------------
// Flash attention, 64-query waves: NO-MAX softmax, Schraudolph fused into
// QK^T MFMA C-op, K-split x2, tiled V, pointer-marching, loads-first.
// Block = one (bh, 128-query tile): wave w: qhalf = w&1 (64 q), khalf = w>>1.
// K/V loads amortized over 4 q-fragments (4 independent MFMA chains).
// ---------------------------------------------------------------------------
__global__ __launch_bounds__(256, 4) void attn_mfma(
    const h16* __restrict__ q, const h16* __restrict__ k,
    const h16* __restrict__ vt, h16* __restrict__ a)
{
    int tid = threadIdx.x;
    int lane = tid & 63, w = tid >> 6;
    int lm = lane & 15, g4 = (lane >> 4) * 4;
    int bid = blockIdx.x;
    int W = (bid & 7) * 128 + (bid >> 3);     // XCD swizzle, bijective over 1024
    int bh = W >> 4;                          // 0..63
    int q128 = W & 15;                        // 128-query tile
    int q0 = q128 * 128 + (w & 1) * 64;
    int khalf = w >> 1;

    v4h qf[4];
#pragma unroll
    for (int j = 0; j < 4; j++)
        qf[j] = *(const v4h*)(q + ((size_t)bh*T_SEQ + q0 + j*16 + lm)*HD + g4);
    const h16* kpl = k  + ((size_t)bh*T_SEQ + khalf*1024 + lm)*HD + g4;
    const h16* vpl = vt + ((size_t)bh*(T_SEQ/16) + khalf*64)*256 + lm*16 + g4;

    v4f accA[4] = {{0,0,0,0},{0,0,0,0},{0,0,0,0},{0,0,0,0}};
    v4f accB[4] = {{0,0,0,0},{0,0,0,0},{0,0,0,0},{0,0,0,0}};
    float la[4] = {0.f,0.f,0.f,0.f}, lb[4] = {0.f,0.f,0.f,0.f};
    const v4f bvec = {BMAGIC, BMAGIC, BMAGIC, BMAGIC};

    for (int kt = 0; kt < 16; kt++) {
        // ---- issue ALL tile loads first (imm offsets off marching bases) ----
        v4h kf[4], vf[4];
#pragma unroll
        for (int m = 0; m < 4; m++) {
            kf[m] = *(const v4h*)(kpl + m*256);
            vf[m] = *(const v4h*)(vpl + m*256);
        }
        kpl += 1024; vpl += 1024;
        __builtin_amdgcn_sched_barrier(0);
        // ---- 4 independent QK->perm->PV chains per m ----
#pragma unroll
        for (int m = 0; m < 4; m++) {
#pragma unroll
            for (int j = 0; j < 4; j++) {
                v4f t = MFMA16(kf[m], qf[j], bvec, 0, 0, 0);
                h2 a0 = pkperm(t[0], t[1]);
                h2 b0 = pkperm(t[2], t[3]);
                la[j] = fdot2p(a0, la[j]);
                lb[j] = fdot2p(b0, lb[j]);
                v4h p = __builtin_shufflevector(a0, b0, 0, 1, 2, 3);
                if (m & 1) accB[j] = MFMA16(vf[m], p, accB[j], 0, 0, 0);
                else       accA[j] = MFMA16(vf[m], p, accA[j], 0, 0, 0);
            }
        }
    }

    // per-wave finalize: group-reduce l (column-uniform), sum acc pairs
    float l[4];
    v4f acc[4];
#pragma unroll
    for (int j = 0; j < 4; j++) {
        float lj = la[j] + lb[j];
        lj += __shfl_xor(lj, 16, 64); lj += __shfl_xor(lj, 32, 64);
        l[j] = lj;
        acc[j] = accA[j] + accB[j];
    }

    // K-split merge via LDS: pure additive. Waves 2,3 publish; 0,1 finish.
    __shared__ float lds[2][64][21];
    if (w >= 2) {
        float* p = lds[w - 2][lane];
#pragma unroll
        for (int j = 0; j < 4; j++) {
            p[j] = l[j];
#pragma unroll
            for (int r = 0; r < 4; r++) p[4 + j*4 + r] = acc[j][r];
        }
    }
    __syncthreads();
    if (w < 2) {
        const float* p = lds[w][lane];
        int b = bh >> 2, h = bh & 3;
#pragma unroll
        for (int j = 0; j < 4; j++) {
            float inv = frcp(l[j] + p[j]);
            v4h o;
#pragma unroll
            for (int r = 0; r < 4; r++)
                o[r] = (h16)((acc[j][r] + p[4 + j*4 + r]) * inv);
            *(v4h*)(a + ((size_t)(b*T_SEQ) + q0 + j*16 + lm)*C_DIM + h*HD + g4) = o;
        }
    }
}

// ---------------------------------------------------------------------------
// Fused tail, FFN split x2, packed weights, loads-first per section.
// ---------------------------------------------------------------------------
__global__ __launch_bounds__(256) void tail_fused(
    const h16* __restrict__ a, const float* __restrict__ x,
    const v4h* __restrict__ wp,
    const float* __restrict__ b1, const float* __restrict__ b2,
    const float* __restrict__ g1, const float* __restrict__ be1,
    const float* __restrict__ g2, const float* __restrict__ be2,
    float* __restrict__ out)
{
    int tid = threadIdx.x;
    int lane = tid & 63, w = tid >> 6;
    int lm = lane & 15, g4 = (lane >> 4) * 4;
    int pair = w >> 1;                 // token tile in block
    int half = w & 1;                  // ffn half
    int t0 = (blockIdx.x * 2 + pair) * 16;

    const v4h* whp = wp + 3072;
    const v4h* wh1 = wp + 4096;
    const v4h* wh2 = wp + 6144;

    v4h af[4];
#pragma unroll
    for (int kt = 0; kt < 4; kt++)
        af[kt] = *(const v4h*)(a + (size_t)(t0 + lm)*C_DIM + kt*16 + g4);

    // ---- proj + residual + LN1 (both halves compute; cheap) ----
    float rvn[4][4];
    v4h x1t[4];
    {
        v4h wf[16];
#pragma unroll
        for (int f = 0; f < 16; f++) wf[f] = whp[f*64 + lane];
        __builtin_amdgcn_sched_barrier(0);
        v4f rv[4];
#pragma unroll
        for (int cn = 0; cn < 4; cn++) {
            v4f acc = {0.f, 0.f, 0.f, 0.f};
#pragma unroll
            for (int kt = 0; kt < 4; kt++)
                acc = MFMA16(wf[cn*4 + kt], af[kt], acc, 0, 0, 0);
            v4f xr = *(const v4f*)(x + (size_t)(t0 + lm)*C_DIM + cn*16 + g4);
            rv[cn] = acc + xr;
        }
        float s = 0.f;
#pragma unroll
        for (int cn = 0; cn < 4; cn++)
#pragma unroll
            for (int i = 0; i < 4; i++) s += rv[cn][i];
        s += __shfl_xor(s, 16, 64); s += __shfl_xor(s, 32, 64);
        float mu = s * (1.f/64.f);
        float qs = 0.f;
#pragma unroll
        for (int cn = 0; cn < 4; cn++)
#pragma unroll
            for (int i = 0; i < 4; i++) { float d = rv[cn][i] - mu; qs += d*d; }
        qs += __shfl_xor(qs, 16, 64); qs += __shfl_xor(qs, 32, 64);
        float is = frsq(qs * (1.f/64.f) + EPS_LN);
#pragma unroll
        for (int cn = 0; cn < 4; cn++) {
            v4f g1v = *(const v4f*)(g1 + cn*16 + g4);
            v4f bev = *(const v4f*)(be1 + cn*16 + g4);
#pragma unroll
            for (int i = 0; i < 4; i++) {
                float vl = (rv[cn][i] - mu) * is * g1v[i] + bev[i];
                rvn[cn][i] = vl;
                x1t[cn][i] = (h16)vl;
            }
        }
    }
    __builtin_amdgcn_sched_barrier(0);

    // ---- FFN1 half + ReLU (4 of 8 nf groups) ----
    v4h ht[4];
    {
        v4h wf[16];
#pragma unroll
        for (int f = 0; f < 16; f++) wf[f] = wh1[(half*16 + f)*64 + lane];
        __builtin_amdgcn_sched_barrier(0);
#pragma unroll
        for (int j = 0; j < 4; j++) {
            int nf = half * 4 + j;
            v4f acc = {0.f, 0.f, 0.f, 0.f};
#pragma unroll
            for (int kt = 0; kt < 4; kt++)
                acc = MFMA16(wf[j*4 + kt], x1t[kt], acc, 0, 0, 0);
            v4f b1v = *(const v4f*)(b1 + nf*16 + g4);
#pragma unroll
            for (int i = 0; i < 4; i++) ht[j][i] = (h16)fmaxf(acc[i] + b1v[i], 0.f);
        }
    }
    __builtin_amdgcn_sched_barrier(0);

    // ---- FFN2 partial over this half's 64 hidden units ----
    float yp[4][4];
    {
        v4h wf[16];
#pragma unroll
        for (int cn = 0; cn < 4; cn++)
#pragma unroll
            for (int j = 0; j < 4; j++)
                wf[cn*4 + j] = wh2[(cn*8 + half*4 + j)*64 + lane];
        __builtin_amdgcn_sched_barrier(0);
#pragma unroll
        for (int cn = 0; cn < 4; cn++) {
            v4f acc = {0.f, 0.f, 0.f, 0.f};
#pragma unroll
            for (int j = 0; j < 4; j++)
                acc = MFMA16(wf[cn*4 + j], ht[j], acc, 0, 0, 0);
#pragma unroll
            for (int i = 0; i < 4; i++) yp[cn][i] = acc[i];
        }
    }

    // ---- merge halves via LDS; half 0 finishes ----
    __shared__ float lds[2][64][17];
    if (half == 1) {
        float* p = lds[pair][lane];
#pragma unroll
        for (int cn = 0; cn < 4; cn++)
#pragma unroll
            for (int i = 0; i < 4; i++) p[cn*4 + i] = yp[cn][i];
    }
    __syncthreads();
    if (half == 0) {
        const float* p = lds[pair][lane];
        float yv[4][4];
#pragma unroll
        for (int cn = 0; cn < 4; cn++) {
            v4f b2v = *(const v4f*)(b2 + cn*16 + g4);
#pragma unroll
            for (int i = 0; i < 4; i++)
                yv[cn][i] = yp[cn][i] + p[cn*4 + i] + b2v[i] + rvn[cn][i];
        }
        float s2 = 0.f;
#pragma unroll
        for (int cn = 0; cn < 4; cn++)
#pragma unroll
            for (int i = 0; i < 4; i++) s2 += yv[cn][i];
        s2 += __shfl_xor(s2, 16, 64); s2 += __shfl_xor(s2, 32, 64);
        float mu2 = s2 * (1.f/64.f);
        float qs2 = 0.f;
#pragma unroll
        for (int cn = 0; cn < 4; cn++)
#pragma unroll
            for (int i = 0; i < 4; i++) { float d = yv[cn][i] - mu2; qs2 += d*d; }
        qs2 += __shfl_xor(qs2, 16, 64); qs2 += __shfl_xor(qs2, 32, 64);
        float is2 = frsq(qs2 * (1.f/64.f) + EPS_LN);
#pragma unroll
        for (int cn = 0; cn < 4; cn++) {
            v4f g2v = *(const v4f*)(g2 + cn*16 + g4);
            v4f bev = *(const v4f*)(be2 + cn*16 + g4);
            v4f o;
#pragma unroll
            for (int i = 0; i < 4; i++) o[i] = (yv[cn][i] - mu2) * is2 * g2v[i] + bev[i];
            *(v4f*)(out + (size_t)(t0 + lm)*C_DIM + cn*16 + g4) = o;
        }
    }
}

// ---------------------------------------------------------------------------
extern "C" void kernel_launch(void* const* d_in, const int* in_sizes, int n_in,
                              void* d_out, int out_size, void* d_ws, size_t ws_size,
                              hipStream_t stream)
{
    const float* x     = (const float*)d_in[0];
    const float* Wqkv  = (const float*)d_in[1];
    const float* Wproj = (const float*)d_in[2];
    const float* W1    = (const float*)d_in[3];
    const float* b1    = (const float*)d_in[4];
    const float* W2    = (const float*)d_in[5];
    const float* b2    = (const float*)d_in[6];
    const float* g1    = (const float*)d_in[7];
    const float* be1   = (const float*)d_in[8];
    const float* g2    = (const float*)d_in[9];
    const float* be2   = (const float*)d_in[10];
    float* out = (float*)d_out;

    const size_t perQ = (size_t)BATCH * N_H * T_SEQ * HD;   // 2M elements
    h16* q   = (h16*)d_ws;
    h16* kk  = q  + perQ;
    h16* vt  = kk + perQ;
    h16* a   = vt + perQ;
    v4h* wp  = (v4h*)(a + (size_t)NTOK * C_DIM);            // 8192 frags, 64 KB

    prep_pack  <<<32,   256, 0, stream>>>(Wqkv, Wproj, W1, W2, wp);
    qkv_gemm   <<<2048, 256, 0, stream>>>(x, wp, q, kk, vt);
    attn_mfma  <<<1024, 256, 0, stream>>>(q, kk, vt, a);
    tail_fused <<<1024, 256, 0, stream>>>(a, x, wp, b1, b2,
                                          g1, be1, g2, be2, out);
}

// Round 20
// 62.884 us; speedup vs baseline: 1.1957x; 1.0141x over previous
//
#include <hip/hip_runtime.h>
#include <hip/hip_bf16.h>
#include <math.h>

typedef _Float16 h16;
typedef h16   v4h __attribute__((ext_vector_type(4)));
typedef h16   h2  __attribute__((ext_vector_type(2)));
typedef float v4f __attribute__((ext_vector_type(4)));

#define T_SEQ 2048
#define BATCH 16
#define NTOK  (BATCH * T_SEQ)
#define C_DIM 64
#define N_H   4
#define HD    16
#define FF    128
#define EPS_LN 1e-5f
#define MFMA16 __builtin_amdgcn_mfma_f32_16x16x16f16
// q pre-scale: hd^-0.5 * log2(e) * 1024 (Schraudolph FMA fused into QK^T MFMA C-op)
#define QSCALE (0.25f * 1.44269504089f * 1024.0f)
#define BMAGIC (12582912.0f + 15316.0f)   // 1.5*2^23 + (15360-44)

static __device__ __forceinline__ float frcp(float x) {
#if __has_builtin(__builtin_amdgcn_rcpf)
    return __builtin_amdgcn_rcpf(x);
#else
    return 1.0f / x;
#endif
}
static __device__ __forceinline__ float frsq(float x) {
#if __has_builtin(__builtin_amdgcn_rsqf)
    return __builtin_amdgcn_rsqf(x);
#else
    return rsqrtf(x);
#endif
}
static __device__ __forceinline__ float fdot2p(h2 a, float acc) {
#if __has_builtin(__builtin_amdgcn_fdot2)
    const h2 one2 = {(h16)1.0f, (h16)1.0f};
    return __builtin_amdgcn_fdot2(a, one2, acc, false);
#else
    return acc + (float)a[0] + (float)a[1];
#endif
}
static __device__ __forceinline__ v4h cvt4(v4f f) {
    v4h r; r[0]=(h16)f[0]; r[1]=(h16)f[1]; r[2]=(h16)f[2]; r[3]=(h16)f[3];
    return r;
}
// pack low-16 (f16 bits) of two Schraudolph f32 results into one h2
static __device__ __forceinline__ h2 pkperm(float t0, float t1) {
    unsigned r = __builtin_amdgcn_perm(__builtin_bit_cast(unsigned, t1),
                                       __builtin_bit_cast(unsigned, t0),
                                       0x05040100u);
    return __builtin_bit_cast(h2, r);
}

// ---------------------------------------------------------------------------
// Weight pack: all four weight matrices -> f16 MFMA-fragment order, once.
// wp[f][lane] (v4h), element i = W[(o*16+lm)*K + kt*16+g4+i].
// Segments: wq [0,3072) | whp [3072,4096) | wh1 [4096,6144) | wh2 [6144,8192)
// ---------------------------------------------------------------------------
__global__ __launch_bounds__(256) void prep_pack(
    const float* __restrict__ Wqkv, const float* __restrict__ Wproj,
    const float* __restrict__ W1,   const float* __restrict__ W2,
    v4h* __restrict__ wp)
{
    int fid = blockIdx.x * 256 + threadIdx.x;   // 0..8191
    int lane = fid & 63;
    int lm = lane & 15, g4 = ((lane >> 4) & 3) * 4;
    int frag = fid >> 6;
    const float* src; int o, kt, K;
    if (fid < 3072)      { int f = frag;      o = f >> 2; kt = f & 3; K = 64;  src = Wqkv;  }
    else if (fid < 4096) { int f = frag - 48; o = f >> 2; kt = f & 3; K = 64;  src = Wproj; }
    else if (fid < 6144) { int f = frag - 64; o = f >> 2; kt = f & 3; K = 64;  src = W1;    }
    else                 { int f = frag - 96; o = f >> 3; kt = f & 7; K = 128; src = W2;    }
    v4f v = *(const v4f*)(src + (o*16 + lm)*K + kt*16 + g4);
    wp[fid] = cvt4(v);
}

// ---------------------------------------------------------------------------
// qkv GEMM: 1 block = 1 token-tile (coalesced 4KB x load -> LDS f16),
// 4 waves = n-split x4 over 12 output columns. Packed weights.
// q pre-scaled by QSCALE. V stored TILED: [bh][key_tile][d16][key16].
// ---------------------------------------------------------------------------
__global__ __launch_bounds__(256) void qkv_gemm(
    const float* __restrict__ x, const v4h* __restrict__ wq,
    h16* __restrict__ q, h16* __restrict__ k, h16* __restrict__ vt)
{
    int tid = threadIdx.x;
    int lane = tid & 63, w = tid >> 6;
    int lm = lane & 15, g4 = (lane >> 4) * 4;
    int tile = blockIdx.x;                  // 0..2047
    int t0 = tile * 16;
    int ng = w;                             // 3 n-values per wave

    // coalesced x load: 256 threads x 16B = the tile's contiguous 4KB
    __shared__ h16 xs[16][72];              // +8 f16 pad per row (bank spread)
    {
        v4f v = *(const v4f*)(x + (size_t)t0 * C_DIM + tid * 4);
        int r = tid >> 4;                   // row (token within tile)
        int c = (tid & 15) * 4;             // col (channel)
        *(v4h*)&xs[r][c] = cvt4(v);
    }
    __syncthreads();

    v4h af[4];
#pragma unroll
    for (int kt = 0; kt < 4; kt++)
        af[kt] = *(const v4h*)&xs[lm][kt*16 + g4];

    int b = t0 >> 11, tl = t0 & (T_SEQ - 1);
#pragma unroll
    for (int j = 0; j < 3; j++) {
        int n = ng * 3 + j;
        v4f acc = {0.f, 0.f, 0.f, 0.f};
#pragma unroll
        for (int kt = 0; kt < 4; kt++)
            acc = MFMA16(af[kt], wq[(n*4 + kt)*64 + lane], acc, 0, 0, 0);
        if (n < 4) {
            h16* qp = q + ((size_t)(b*N_H + n)*T_SEQ + tl + g4)*HD + lm;
#pragma unroll
            for (int r = 0; r < 4; r++) qp[r*HD] = (h16)(acc[r] * QSCALE);
        } else if (n < 8) {
            h16* kp = k + ((size_t)(b*N_H + (n-4))*T_SEQ + tl + g4)*HD + lm;
#pragma unroll
            for (int r = 0; r < 4; r++) kp[r*HD] = (h16)acc[r];
        } else {
            v4h pk;
#pragma unroll
            for (int r = 0; r < 4; r++) pk[r] = (h16)acc[r];
            *(v4h*)(vt + ((size_t)(b*N_H + (n-8))*(T_SEQ/16) + (tl >> 4))*256
                       + lm*16 + g4) = pk;
        }
    }
}

// ---------------------------------------------------------------------------
// Flash attention, 128-query waves: NO-MAX softmax, Schraudolph fused into
// QK^T MFMA C-op, K-split x2, tiled V, pointer-marching, loads-first.
// Block = one (bh, 256-query tile): wave w: qhalf = w&1 (128 q), khalf = w>>1.
// K/V loads amortized over 8 q-fragments (8 independent MFMA chains).
// ---------------------------------------------------------------------------
__global__ __launch_bounds__(256, 2) void attn_mfma(
    const h16* __restrict__ q, const h16* __restrict__ k,
    const h16* __restrict__ vt, h16* __restrict__ a)
{
    int tid = threadIdx.x;
    int lane = tid & 63, w = tid >> 6;
    int lm = lane & 15, g4 = (lane >> 4) * 4;
    int bid = blockIdx.x;
    int W = (bid & 7) * 64 + (bid >> 3);      // XCD swizzle, bijective over 512
    int bh = W >> 3;                          // 0..63
    int q256 = W & 7;                         // 256-query tile
    int q0 = q256 * 256 + (w & 1) * 128;
    int khalf = w >> 1;

    v4h qf[8];
#pragma unroll
    for (int j = 0; j < 8; j++)
        qf[j] = *(const v4h*)(q + ((size_t)bh*T_SEQ + q0 + j*16 + lm)*HD + g4);
    const h16* kpl = k  + ((size_t)bh*T_SEQ + khalf*1024 + lm)*HD + g4;
    const h16* vpl = vt + ((size_t)bh*(T_SEQ/16) + khalf*64)*256 + lm*16 + g4;

    v4f acc[8] = {{0,0,0,0},{0,0,0,0},{0,0,0,0},{0,0,0,0},
                  {0,0,0,0},{0,0,0,0},{0,0,0,0},{0,0,0,0}};
    float l[8] = {0.f,0.f,0.f,0.f,0.f,0.f,0.f,0.f};
    const v4f bvec = {BMAGIC, BMAGIC, BMAGIC, BMAGIC};

    for (int kt = 0; kt < 16; kt++) {
        // ---- issue ALL tile loads first (imm offsets off marching bases) ----
        v4h kf[4], vf[4];
#pragma unroll
        for (int m = 0; m < 4; m++) {
            kf[m] = *(const v4h*)(kpl + m*256);
            vf[m] = *(const v4h*)(vpl + m*256);
        }
        kpl += 1024; vpl += 1024;
        __builtin_amdgcn_sched_barrier(0);
        // ---- 8 independent QK->perm->PV chains per m ----
#pragma unroll
        for (int m = 0; m < 4; m++) {
#pragma unroll
            for (int j = 0; j < 8; j++) {
                v4f t = MFMA16(kf[m], qf[j], bvec, 0, 0, 0);
                h2 a0 = pkperm(t[0], t[1]);
                h2 b0 = pkperm(t[2], t[3]);
                l[j] = fdot2p(a0, l[j]);
                l[j] = fdot2p(b0, l[j]);
                v4h p = __builtin_shufflevector(a0, b0, 0, 1, 2, 3);
                acc[j] = MFMA16(vf[m], p, acc[j], 0, 0, 0);
            }
        }
    }

    // per-wave finalize: group-reduce l (column-uniform)
#pragma unroll
    for (int j = 0; j < 8; j++) {
        float lj = l[j];
        lj += __shfl_xor(lj, 16, 64); lj += __shfl_xor(lj, 32, 64);
        l[j] = lj;
    }

    // K-split merge via LDS: pure additive. Waves 2,3 publish; 0,1 finish.
    __shared__ float lds[2][64][41];
    if (w >= 2) {
        float* p = lds[w - 2][lane];
#pragma unroll
        for (int j = 0; j < 8; j++) {
            p[j] = l[j];
#pragma unroll
            for (int r = 0; r < 4; r++) p[8 + j*4 + r] = acc[j][r];
        }
    }
    __syncthreads();
    if (w < 2) {
        const float* p = lds[w][lane];
        int b = bh >> 2, h = bh & 3;
#pragma unroll
        for (int j = 0; j < 8; j++) {
            float inv = frcp(l[j] + p[j]);
            v4h o;
#pragma unroll
            for (int r = 0; r < 4; r++)
                o[r] = (h16)((acc[j][r] + p[8 + j*4 + r]) * inv);
            *(v4h*)(a + ((size_t)(b*T_SEQ) + q0 + j*16 + lm)*C_DIM + h*HD + g4) = o;
        }
    }
}

// ---------------------------------------------------------------------------
// Fused tail, FFN split x2, packed weights, loads-first per section.
// ---------------------------------------------------------------------------
__global__ __launch_bounds__(256) void tail_fused(
    const h16* __restrict__ a, const float* __restrict__ x,
    const v4h* __restrict__ wp,
    const float* __restrict__ b1, const float* __restrict__ b2,
    const float* __restrict__ g1, const float* __restrict__ be1,
    const float* __restrict__ g2, const float* __restrict__ be2,
    float* __restrict__ out)
{
    int tid = threadIdx.x;
    int lane = tid & 63, w = tid >> 6;
    int lm = lane & 15, g4 = (lane >> 4) * 4;
    int pair = w >> 1;                 // token tile in block
    int half = w & 1;                  // ffn half
    int t0 = (blockIdx.x * 2 + pair) * 16;

    const v4h* whp = wp + 3072;
    const v4h* wh1 = wp + 4096;
    const v4h* wh2 = wp + 6144;

    v4h af[4];
#pragma unroll
    for (int kt = 0; kt < 4; kt++)
        af[kt] = *(const v4h*)(a + (size_t)(t0 + lm)*C_DIM + kt*16 + g4);

    // ---- proj + residual + LN1 (both halves compute; cheap) ----
    float rvn[4][4];
    v4h x1t[4];
    {
        v4h wf[16];
#pragma unroll
        for (int f = 0; f < 16; f++) wf[f] = whp[f*64 + lane];
        __builtin_amdgcn_sched_barrier(0);
        v4f rv[4];
#pragma unroll
        for (int cn = 0; cn < 4; cn++) {
            v4f acc = {0.f, 0.f, 0.f, 0.f};
#pragma unroll
            for (int kt = 0; kt < 4; kt++)
                acc = MFMA16(wf[cn*4 + kt], af[kt], acc, 0, 0, 0);
            v4f xr = *(const v4f*)(x + (size_t)(t0 + lm)*C_DIM + cn*16 + g4);
            rv[cn] = acc + xr;
        }
        float s = 0.f;
#pragma unroll
        for (int cn = 0; cn < 4; cn++)
#pragma unroll
            for (int i = 0; i < 4; i++) s += rv[cn][i];
        s += __shfl_xor(s, 16, 64); s += __shfl_xor(s, 32, 64);
        float mu = s * (1.f/64.f);
        float qs = 0.f;
#pragma unroll
        for (int cn = 0; cn < 4; cn++)
#pragma unroll
            for (int i = 0; i < 4; i++) { float d = rv[cn][i] - mu; qs += d*d; }
        qs += __shfl_xor(qs, 16, 64); qs += __shfl_xor(qs, 32, 64);
        float is = frsq(qs * (1.f/64.f) + EPS_LN);
#pragma unroll
        for (int cn = 0; cn < 4; cn++) {
            v4f g1v = *(const v4f*)(g1 + cn*16 + g4);
            v4f bev = *(const v4f*)(be1 + cn*16 + g4);
#pragma unroll
            for (int i = 0; i < 4; i++) {
                float vl = (rv[cn][i] - mu) * is * g1v[i] + bev[i];
                rvn[cn][i] = vl;
                x1t[cn][i] = (h16)vl;
            }
        }
    }
    __builtin_amdgcn_sched_barrier(0);

    // ---- FFN1 half + ReLU (4 of 8 nf groups) ----
    v4h ht[4];
    {
        v4h wf[16];
#pragma unroll
        for (int f = 0; f < 16; f++) wf[f] = wh1[(half*16 + f)*64 + lane];
        __builtin_amdgcn_sched_barrier(0);
#pragma unroll
        for (int j = 0; j < 4; j++) {
            int nf = half * 4 + j;
            v4f acc = {0.f, 0.f, 0.f, 0.f};
#pragma unroll
            for (int kt = 0; kt < 4; kt++)
                acc = MFMA16(wf[j*4 + kt], x1t[kt], acc, 0, 0, 0);
            v4f b1v = *(const v4f*)(b1 + nf*16 + g4);
#pragma unroll
            for (int i = 0; i < 4; i++) ht[j][i] = (h16)fmaxf(acc[i] + b1v[i], 0.f);
        }
    }
    __builtin_amdgcn_sched_barrier(0);

    // ---- FFN2 partial over this half's 64 hidden units ----
    float yp[4][4];
    {
        v4h wf[16];
#pragma unroll
        for (int cn = 0; cn < 4; cn++)
#pragma unroll
            for (int j = 0; j < 4; j++)
                wf[cn*4 + j] = wh2[(cn*8 + half*4 + j)*64 + lane];
        __builtin_amdgcn_sched_barrier(0);
#pragma unroll
        for (int cn = 0; cn < 4; cn++) {
            v4f acc = {0.f, 0.f, 0.f, 0.f};
#pragma unroll
            for (int j = 0; j < 4; j++)
                acc = MFMA16(wf[cn*4 + j], ht[j], acc, 0, 0, 0);
#pragma unroll
            for (int i = 0; i < 4; i++) yp[cn][i] = acc[i];
        }
    }

    // ---- merge halves via LDS; half 0 finishes ----
    __shared__ float lds[2][64][17];
    if (half == 1) {
        float* p = lds[pair][lane];
#pragma unroll
        for (int cn = 0; cn < 4; cn++)
#pragma unroll
            for (int i = 0; i < 4; i++) p[cn*4 + i] = yp[cn][i];
    }
    __syncthreads();
    if (half == 0) {
        const float* p = lds[pair][lane];
        float yv[4][4];
#pragma unroll
        for (int cn = 0; cn < 4; cn++) {
            v4f b2v = *(const v4f*)(b2 + cn*16 + g4);
#pragma unroll
            for (int i = 0; i < 4; i++)
                yv[cn][i] = yp[cn][i] + p[cn*4 + i] + b2v[i] + rvn[cn][i];
        }
        float s2 = 0.f;
#pragma unroll
        for (int cn = 0; cn < 4; cn++)
#pragma unroll
            for (int i = 0; i < 4; i++) s2 += yv[cn][i];
        s2 += __shfl_xor(s2, 16, 64); s2 += __shfl_xor(s2, 32, 64);
        float mu2 = s2 * (1.f/64.f);
        float qs2 = 0.f;
#pragma unroll
        for (int cn = 0; cn < 4; cn++)
#pragma unroll
            for (int i = 0; i < 4; i++) { float d = yv[cn][i] - mu2; qs2 += d*d; }
        qs2 += __shfl_xor(qs2, 16, 64); qs2 += __shfl_xor(qs2, 32, 64);
        float is2 = frsq(qs2 * (1.f/64.f) + EPS_LN);
#pragma unroll
        for (int cn = 0; cn < 4; cn++) {
            v4f g2v = *(const v4f*)(g2 + cn*16 + g4);
            v4f bev = *(const v4f*)(be2 + cn*16 + g4);
            v4f o;
#pragma unroll
            for (int i = 0; i < 4; i++) o[i] = (yv[cn][i] - mu2) * is2 * g2v[i] + bev[i];
            *(v4f*)(out + (size_t)(t0 + lm)*C_DIM + cn*16 + g4) = o;
        }
    }
}

// ---------------------------------------------------------------------------
extern "C" void kernel_launch(void* const* d_in, const int* in_sizes, int n_in,
                              void* d_out, int out_size, void* d_ws, size_t ws_size,
                              hipStream_t stream)
{
    const float* x     = (const float*)d_in[0];
    const float* Wqkv  = (const float*)d_in[1];
    const float* Wproj = (const float*)d_in[2];
    const float* W1    = (const float*)d_in[3];
    const float* b1    = (const float*)d_in[4];
    const float* W2    = (const float*)d_in[5];
    const float* b2    = (const float*)d_in[6];
    const float* g1    = (const float*)d_in[7];
    const float* be1   = (const float*)d_in[8];
    const float* g2    = (const float*)d_in[9];
    const float* be2   = (const float*)d_in[10];
    float* out = (float*)d_out;

    const size_t perQ = (size_t)BATCH * N_H * T_SEQ * HD;   // 2M elements
    h16* q   = (h16*)d_ws;
    h16* kk  = q  + perQ;
    h16* vt  = kk + perQ;
    h16* a   = vt + perQ;
    v4h* wp  = (v4h*)(a + (size_t)NTOK * C_DIM);            // 8192 frags, 64 KB

    prep_pack  <<<32,   256, 0, stream>>>(Wqkv, Wproj, W1, W2, wp);
    qkv_gemm   <<<2048, 256, 0, stream>>>(x, wp, q, kk, vt);
    attn_mfma  <<<512,  256, 0, stream>>>(q, kk, vt, a);
    tail_fused <<<1024, 256, 0, stream>>>(a, x, wp, b1, b2,
                                          g1, be1, g2, be2, out);
}